// Round 6
// baseline (626.653 us; speedup 1.0000x reference)
//
#include <hip/hip_runtime.h>
#include <hip/hip_bf16.h>

#define N_NODES 50000
#define N_EDGES 800000
#define IN_CH 128
#define HID 256
#define PROJ 128
#define N_GRAPHS 512
#define NTHR 1024
#define NCH ((N_NODES + NTHR - 1) / NTHR)  // 49 scan chunks

typedef short bf16x8 __attribute__((ext_vector_type(8)));
typedef float f32x4 __attribute__((ext_vector_type(4)));

__device__ __forceinline__ float bf2f(unsigned short u) {
  union { unsigned int i; float f; } x;
  x.i = ((unsigned int)u) << 16;
  return x.f;
}
__device__ __forceinline__ unsigned short f2bf(float f) {
  __hip_bfloat16 h = __float2bfloat16(f);  // RNE
  return *reinterpret_cast<unsigned short*>(&h);
}
__device__ __forceinline__ void load_lds16(const void* g, void* l) {
  __builtin_amdgcn_global_load_lds(
      (const __attribute__((address_space(1))) void*)g,
      (__attribute__((address_space(3))) void*)l, 16, 0, 0);
}

// Device-wide generation barrier. bar[0]=arrive count, bar[1]=generation.
// All blocks co-resident (grid == #CUs, 1 block/CU by construction).
__device__ __forceinline__ void gbar(int* bar, int nblk) {
  __syncthreads();  // drains this block's vmcnt (compiler emits waitcnt)
  if (threadIdx.x == 0) {
    __threadfence();  // device-scope release of our writes
    int g = __hip_atomic_load(&bar[1], __ATOMIC_RELAXED, __HIP_MEMORY_SCOPE_AGENT);
    int old = __hip_atomic_fetch_add(&bar[0], 1, __ATOMIC_ACQ_REL,
                                     __HIP_MEMORY_SCOPE_AGENT);
    if (old == nblk - 1) {
      __hip_atomic_store(&bar[0], 0, __ATOMIC_RELAXED, __HIP_MEMORY_SCOPE_AGENT);
      __hip_atomic_store(&bar[1], g + 1, __ATOMIC_RELEASE,
                         __HIP_MEMORY_SCOPE_AGENT);
    } else {
      while (__hip_atomic_load(&bar[1], __ATOMIC_RELAXED,
                               __HIP_MEMORY_SCOPE_AGENT) == g)
        __builtin_amdgcn_s_sleep(2);
    }
    __threadfence();  // device-scope acquire (invalidate L1/L2 stale lines)
  }
  __syncthreads();
}

// ---------------------------------------------------------------------------
// Pull-gather with fused self-term, one wave per node, 8x unrolled.
// ---------------------------------------------------------------------------
template <int C>
__device__ __forceinline__ void gather_phase(const unsigned short* feat,
                                             const int* ptr, const int* esrc,
                                             unsigned short* out, int nblk) {
  const int lane = threadIdx.x & 63;
  const int wid = blockIdx.x * (NTHR / 64) + (threadIdx.x >> 6);
  const int nw = nblk * (NTHR / 64);
  for (int node = wid; node < N_NODES; node += nw) {
    const int beg = __builtin_amdgcn_readfirstlane(ptr[node]);
    const int end = __builtin_amdgcn_readfirstlane(ptr[node + 1]);
    if constexpr (C == 256) {
      const ushort4* u4 = reinterpret_cast<const ushort4*>(feat);
      ushort4 sv = u4[(size_t)node * 64 + lane];
      float a0 = bf2f(sv.x), a1 = bf2f(sv.y), a2 = bf2f(sv.z), a3 = bf2f(sv.w);
      int e = beg;
      for (; e + 8 <= end; e += 8) {
        int s0 = esrc[e + 0], s1 = esrc[e + 1], s2 = esrc[e + 2], s3 = esrc[e + 3];
        int s4 = esrc[e + 4], s5 = esrc[e + 5], s6 = esrc[e + 6], s7 = esrc[e + 7];
        ushort4 v0 = u4[(size_t)s0 * 64 + lane], v1 = u4[(size_t)s1 * 64 + lane];
        ushort4 v2 = u4[(size_t)s2 * 64 + lane], v3 = u4[(size_t)s3 * 64 + lane];
        ushort4 v4 = u4[(size_t)s4 * 64 + lane], v5 = u4[(size_t)s5 * 64 + lane];
        ushort4 v6 = u4[(size_t)s6 * 64 + lane], v7 = u4[(size_t)s7 * 64 + lane];
        a0 += (bf2f(v0.x) + bf2f(v1.x)) + (bf2f(v2.x) + bf2f(v3.x)) +
              (bf2f(v4.x) + bf2f(v5.x)) + (bf2f(v6.x) + bf2f(v7.x));
        a1 += (bf2f(v0.y) + bf2f(v1.y)) + (bf2f(v2.y) + bf2f(v3.y)) +
              (bf2f(v4.y) + bf2f(v5.y)) + (bf2f(v6.y) + bf2f(v7.y));
        a2 += (bf2f(v0.z) + bf2f(v1.z)) + (bf2f(v2.z) + bf2f(v3.z)) +
              (bf2f(v4.z) + bf2f(v5.z)) + (bf2f(v6.z) + bf2f(v7.z));
        a3 += (bf2f(v0.w) + bf2f(v1.w)) + (bf2f(v2.w) + bf2f(v3.w)) +
              (bf2f(v4.w) + bf2f(v5.w)) + (bf2f(v6.w) + bf2f(v7.w));
      }
      for (; e < end; ++e) {
        int s = esrc[e];
        ushort4 v = u4[(size_t)s * 64 + lane];
        a0 += bf2f(v.x); a1 += bf2f(v.y); a2 += bf2f(v.z); a3 += bf2f(v.w);
      }
      ushort4 o = {f2bf(a0), f2bf(a1), f2bf(a2), f2bf(a3)};
      reinterpret_cast<ushort4*>(out)[(size_t)node * 64 + lane] = o;
    } else {
      const ushort2* u2 = reinterpret_cast<const ushort2*>(feat);
      ushort2 sv = u2[(size_t)node * 64 + lane];
      float a0 = bf2f(sv.x), a1 = bf2f(sv.y);
      int e = beg;
      for (; e + 8 <= end; e += 8) {
        int s0 = esrc[e + 0], s1 = esrc[e + 1], s2 = esrc[e + 2], s3 = esrc[e + 3];
        int s4 = esrc[e + 4], s5 = esrc[e + 5], s6 = esrc[e + 6], s7 = esrc[e + 7];
        ushort2 v0 = u2[(size_t)s0 * 64 + lane], v1 = u2[(size_t)s1 * 64 + lane];
        ushort2 v2 = u2[(size_t)s2 * 64 + lane], v3 = u2[(size_t)s3 * 64 + lane];
        ushort2 v4 = u2[(size_t)s4 * 64 + lane], v5 = u2[(size_t)s5 * 64 + lane];
        ushort2 v6 = u2[(size_t)s6 * 64 + lane], v7 = u2[(size_t)s7 * 64 + lane];
        a0 += (bf2f(v0.x) + bf2f(v1.x)) + (bf2f(v2.x) + bf2f(v3.x)) +
              (bf2f(v4.x) + bf2f(v5.x)) + (bf2f(v6.x) + bf2f(v7.x));
        a1 += (bf2f(v0.y) + bf2f(v1.y)) + (bf2f(v2.y) + bf2f(v3.y)) +
              (bf2f(v4.y) + bf2f(v5.y)) + (bf2f(v6.y) + bf2f(v7.y));
      }
      for (; e < end; ++e) {
        int s = esrc[e];
        ushort2 v = u2[(size_t)s * 64 + lane];
        a0 += bf2f(v.x); a1 += bf2f(v.y);
      }
      ushort2 o = {f2bf(a0), f2bf(a1)};
      reinterpret_cast<ushort2*>(out)[(size_t)node * 64 + lane] = o;
    }
  }
}

// ---------------------------------------------------------------------------
// MFMA GEMM phase: C[M][256] = relu(A[M][K] @ W + bias). 128x128 tiles,
// 16 waves (4x4), BK=64 double-buffered global_load_lds with XOR chunk
// swizzle via pre-swizzled global source (LDS dest stays linear).
// LDS: A 2x16KB @ [0,32K), B 2x16KB @ [32K,64K).
// ---------------------------------------------------------------------------
template <int K>
__device__ __forceinline__ void gemm_phase(const unsigned short* A,
                                           const unsigned short* Bt,
                                           const float* bias,
                                           unsigned short* C, char* smem,
                                           int nblk) {
  constexpr int BK = 64, NT = K / BK;
  constexpr int NTILES = ((N_NODES + 127) / 128) * 2;  // 391 M-tiles x 2 N-tiles
  const int tid = threadIdx.x;
  const int l = tid & 63;
  const int w = tid >> 6;  // 0..15
  const int wm = w >> 2, wn = w & 3;
  const int rr = l >> 3;        // row within 8-row group
  const int kg = (l & 7) ^ rr;  // pre-swizzled source chunk
  for (int tile = blockIdx.x; tile < NTILES; tile += nblk) {
    const int row0 = (tile >> 1) * 128;
    const int col0 = (tile & 1) * 128;
    f32x4 acc[2][2] = {};
    auto stage = [&](int buf, int t) {
      const int row = w * 8 + rr;  // 0..127
      int ra = row0 + row;
      if (ra > N_NODES - 1) ra = N_NODES - 1;
      load_lds16(A + (size_t)ra * K + t * BK + kg * 8,
                 smem + buf * 16384 + w * 1024);
      const int cb = col0 + row;  // N=256 exact, no clamp needed
      load_lds16(Bt + (size_t)cb * K + t * BK + kg * 8,
                 smem + 32768 + buf * 16384 + w * 1024);
    };
    auto compute = [&](int buf) {
#pragma unroll
      for (int kk = 0; kk < 2; ++kk) {
        const int kc = kk * 4 + (l >> 4);
        bf16x8 a[2], b[2];
#pragma unroll
        for (int m = 0; m < 2; ++m) {
          int row = wm * 32 + m * 16 + (l & 15);
          a[m] = *reinterpret_cast<const bf16x8*>(
              smem + buf * 16384 + row * 128 + (kc ^ (row & 7)) * 16);
        }
#pragma unroll
        for (int n = 0; n < 2; ++n) {
          int col = wn * 32 + n * 16 + (l & 15);
          b[n] = *reinterpret_cast<const bf16x8*>(
              smem + 32768 + buf * 16384 + col * 128 + (kc ^ (col & 7)) * 16);
        }
#pragma unroll
        for (int m = 0; m < 2; ++m)
#pragma unroll
          for (int n = 0; n < 2; ++n)
            acc[m][n] = __builtin_amdgcn_mfma_f32_16x16x32_bf16(
                a[m], b[n], acc[m][n], 0, 0, 0);
      }
    };
    stage(0, 0);
    __syncthreads();
#pragma unroll
    for (int t = 0; t < NT; ++t) {
      const int cur = t & 1;
      if (t + 1 < NT) stage(cur ^ 1, t + 1);
      compute(cur);
      __syncthreads();
    }
    // epilogue: C/D layout col=lane&15, row=(lane>>4)*4+j
#pragma unroll
    for (int n = 0; n < 2; ++n) {
      int gc = col0 + wn * 32 + n * 16 + (l & 15);
      float bv = bias[gc];
#pragma unroll
      for (int m = 0; m < 2; ++m) {
        int rbase = row0 + wm * 32 + m * 16 + (l >> 4) * 4;
#pragma unroll
        for (int j = 0; j < 4; ++j) {
          int r = rbase + j;
          if (r < N_NODES) {
            float v = fmaxf(acc[m][n][j] + bv, 0.f);
            C[(size_t)r * 256 + gc] = f2bf(v);
          }
        }
      }
    }
  }
}

// ---------------------------------------------------------------------------
// The mega-kernel: whole pipeline, device-wide barriers between phases.
// ---------------------------------------------------------------------------
__global__ void __launch_bounds__(NTHR, 4) mega_kernel(
    const float* x, const int* src, const int* dst, const int* batch,
    const float* W1, const float* b1, const float* W2, const float* b2,
    const float* P1w, const float* pb1, const float* P2w, const float* pb2,
    int* bar, int* cnt, int* ptr, int* cursor, int* esrc, int* bsum, int* boff,
    unsigned short* xb, unsigned short* xa, unsigned short* h1,
    unsigned short* ha, unsigned short* h2, unsigned short* Wt1,
    unsigned short* Wt2, float* hg, float* t1, float* z, int nblk) {
  __shared__ char smem[65536];
  const int tid = threadIdx.x;
  const int gt = blockIdx.x * NTHR + tid;
  const int T = nblk * NTHR;

  // ---- P1: x->bf16, W1/W2 -> transposed bf16, edge count (cnt pre-zeroed) --
  for (int i = gt; i < N_NODES * IN_CH / 4; i += T) {
    float4 v = reinterpret_cast<const float4*>(x)[i];
    ushort4 o = {f2bf(v.x), f2bf(v.y), f2bf(v.z), f2bf(v.w)};
    reinterpret_cast<ushort4*>(xb)[i] = o;
  }
  for (int i = gt; i < IN_CH * HID; i += T) {
    int k = i >> 8, n = i & 255;
    Wt1[n * IN_CH + k] = f2bf(W1[i]);
  }
  for (int i = gt; i < HID * HID; i += T) {
    int k = i >> 8, n = i & 255;
    Wt2[n * HID + k] = f2bf(W2[i]);
  }
  for (int e = gt; e < N_EDGES; e += T) atomicAdd(&cnt[dst[e]], 1);
  gbar(bar, nblk);

  // ---- P2: block-local scan of 1024-chunks ----
  {
    int* slds = (int*)smem;
    for (int b = blockIdx.x; b < NCH; b += nblk) {
      const int i = b * NTHR + tid;
      int v = (i < N_NODES) ? cnt[i] : 0;
      slds[tid] = v;
      __syncthreads();
      for (int o = 1; o < NTHR; o <<= 1) {
        int tv = (tid >= o) ? slds[tid - o] : 0;
        __syncthreads();
        slds[tid] += tv;
        __syncthreads();
      }
      if (i < N_NODES) ptr[i] = slds[tid] - v;  // exclusive within chunk
      if (tid == NTHR - 1) bsum[b] = slds[NTHR - 1];
      __syncthreads();
    }
  }
  gbar(bar, nblk);

  // ---- P3: block 0 scans chunk sums ----
  if (blockIdx.x == 0) {
    int* slds = (int*)smem;
    int v = (tid < NCH) ? bsum[tid] : 0;
    slds[tid] = v;
    __syncthreads();
    for (int o = 1; o < NTHR; o <<= 1) {
      int tv = (tid >= o) ? slds[tid - o] : 0;
      __syncthreads();
      slds[tid] += tv;
      __syncthreads();
    }
    if (tid < NCH) boff[tid] = slds[tid] - v;
    if (tid == NTHR - 1) ptr[N_NODES] = slds[NTHR - 1];
  }
  gbar(bar, nblk);

  // ---- P4: apply chunk offsets; init fill cursors ----
  for (int b = blockIdx.x; b < NCH; b += nblk) {
    int i = b * NTHR + tid;
    if (i < N_NODES) {
      int v = ptr[i] + boff[b];
      ptr[i] = v;
      cursor[i] = v;
    }
  }
  gbar(bar, nblk);

  // ---- P5: fill CSR edge lists ----
  for (int e = gt; e < N_EDGES; e += T) {
    int pos = atomicAdd(&cursor[dst[e]], 1);
    esrc[pos] = src[e];
  }
  gbar(bar, nblk);

  // ---- P6..P9: gather1, gemm1, gather2, gemm2 ----
  gather_phase<IN_CH>(xb, ptr, esrc, xa, nblk);
  gbar(bar, nblk);
  gemm_phase<IN_CH>(xa, Wt1, b1, h1, smem, nblk);
  gbar(bar, nblk);
  gather_phase<HID>(h1, ptr, esrc, ha, nblk);
  gbar(bar, nblk);
  gemm_phase<HID>(ha, Wt2, b2, h2, smem, nblk);
  gbar(bar, nblk);

  // ---- P10: mean pool (batch sorted; 2 graphs per block via 256-thr groups)
  {
    const int q = tid >> 8;
    const int c = tid & 255;
    for (int g0 = blockIdx.x * 2; g0 < N_GRAPHS; g0 += nblk * 2) {
      if (q < 2) {
        const int g = g0 + q;
        int lo = 0, hi = N_NODES;
        while (lo < hi) { int mid = (lo + hi) >> 1; if (batch[mid] < g) lo = mid + 1; else hi = mid; }
        const int s = lo;
        lo = 0; hi = N_NODES;
        while (lo < hi) { int mid = (lo + hi) >> 1; if (batch[mid] < g + 1) lo = mid + 1; else hi = mid; }
        const int e2 = lo;
        float A0 = 0.f, A1 = 0.f, A2 = 0.f, A3 = 0.f;
        int n2 = s;
        for (; n2 + 4 <= e2; n2 += 4) {
          A0 += bf2f(h2[(size_t)(n2 + 0) * 256 + c]);
          A1 += bf2f(h2[(size_t)(n2 + 1) * 256 + c]);
          A2 += bf2f(h2[(size_t)(n2 + 2) * 256 + c]);
          A3 += bf2f(h2[(size_t)(n2 + 3) * 256 + c]);
        }
        for (; n2 < e2; ++n2) A0 += bf2f(h2[(size_t)n2 * 256 + c]);
        float acc2 = (A0 + A1) + (A2 + A3);
        hg[g * 256 + c] = acc2 / fmaxf((float)(e2 - s), 1.f);
      }
    }
  }
  gbar(bar, nblk);

  // ---- P11: head1 t1 = relu(hg @ P1 + pb1), 2 rows/block, k-split x4 ----
  {
    float* part = (float*)smem;  // [4][2][256]
    const int q = tid >> 8, n = tid & 255;
    for (int r0 = blockIdx.x * 2; r0 < N_GRAPHS; r0 += nblk * 2) {
      float p0 = 0.f, p1 = 0.f;
      const int k0 = q * 64;
      for (int k = k0; k < k0 + 64; ++k) {
        float wv = P1w[k * 256 + n];
        p0 = fmaf(hg[r0 * 256 + k], wv, p0);
        p1 = fmaf(hg[(r0 + 1) * 256 + k], wv, p1);
      }
      part[(q * 2 + 0) * 256 + n] = p0;
      part[(q * 2 + 1) * 256 + n] = p1;
      __syncthreads();
      if (tid < 512) {
        int r = tid >> 8, nn = tid & 255;
        float ssum = part[(0 + r) * 256 + nn] + part[(2 + r) * 256 + nn] +
                     part[(4 + r) * 256 + nn] + part[(6 + r) * 256 + nn];
        ssum += pb1[nn];
        t1[(r0 + r) * 256 + nn] = fmaxf(ssum, 0.f);
      }
      __syncthreads();
    }
  }
  gbar(bar, nblk);

  // ---- P12: head2 z = t1 @ P2 + pb2, 2 rows/block, k-split x8 ----
  {
    float* part = (float*)smem;  // [8][2][128]
    const int q = tid >> 7, n = tid & 127;
    for (int r0 = blockIdx.x * 2; r0 < N_GRAPHS; r0 += nblk * 2) {
      float p0 = 0.f, p1 = 0.f;
      const int k0 = q * 32;
      for (int k = k0; k < k0 + 32; ++k) {
        float wv = P2w[k * 128 + n];
        p0 = fmaf(t1[r0 * 256 + k], wv, p0);
        p1 = fmaf(t1[(r0 + 1) * 256 + k], wv, p1);
      }
      part[(q * 2 + 0) * 128 + n] = p0;
      part[(q * 2 + 1) * 128 + n] = p1;
      __syncthreads();
      if (tid < 256) {
        int r = tid >> 7, nn = tid & 127;
        float ssum = 0.f;
#pragma unroll
        for (int qq = 0; qq < 8; ++qq) ssum += part[(qq * 2 + r) * 128 + nn];
        ssum += pb2[nn];
        z[(r0 + r) * 128 + nn] = ssum;
      }
      __syncthreads();
    }
  }
}

// ---------------------------------------------------------------------------
extern "C" void kernel_launch(void* const* d_in, const int* in_sizes, int n_in,
                              void* d_out, int out_size, void* d_ws,
                              size_t ws_size, hipStream_t stream) {
  const float* x = (const float*)d_in[0];
  const int* edge = (const int*)d_in[1];
  const int* batch = (const int*)d_in[2];
  const float* W1 = (const float*)d_in[3];
  const float* b1 = (const float*)d_in[4];
  const float* W2 = (const float*)d_in[5];
  const float* b2 = (const float*)d_in[6];
  const float* P1 = (const float*)d_in[7];
  const float* pb1 = (const float*)d_in[8];
  const float* P2 = (const float*)d_in[9];
  const float* pb2 = (const float*)d_in[10];
  const int* src = edge;
  const int* dst = edge + N_EDGES;

  char* ws = (char*)d_ws;
  size_t off = 0;
  auto alloc = [&](size_t bytes) {
    void* p = ws + off;
    off += (bytes + 255) & ~(size_t)255;
    return p;
  };
  // bar + cnt first and contiguous: one memset initializes both.
  int* bar = (int*)alloc(256);                       // bar[0]=count, bar[1]=gen
  int* cnt = (int*)alloc((size_t)N_NODES * 4);
  int* ptr = (int*)alloc((size_t)(N_NODES + 1) * 4);
  int* cursor = (int*)alloc((size_t)N_NODES * 4);
  int* esrc = (int*)alloc((size_t)N_EDGES * 4);
  int* bsum = (int*)alloc(NCH * 4);
  int* boff = (int*)alloc(NCH * 4);
  unsigned short* xb = (unsigned short*)alloc((size_t)N_NODES * IN_CH * 2);
  unsigned short* xa = (unsigned short*)alloc((size_t)N_NODES * IN_CH * 2);
  unsigned short* h1 = (unsigned short*)alloc((size_t)N_NODES * HID * 2);
  unsigned short* ha = (unsigned short*)alloc((size_t)N_NODES * HID * 2);
  unsigned short* h2 = (unsigned short*)alloc((size_t)N_NODES * HID * 2);
  unsigned short* Wt1 = (unsigned short*)alloc((size_t)HID * IN_CH * 2);
  unsigned short* Wt2 = (unsigned short*)alloc((size_t)HID * HID * 2);
  float* hg = (float*)alloc((size_t)N_GRAPHS * HID * 4);
  float* t1 = (float*)alloc((size_t)N_GRAPHS * HID * 4);
  float* z = (float*)d_out;

  // zero barrier state + edge counters in one memset (bar,cnt contiguous)
  hipMemsetAsync(bar, 0, 256 + (size_t)N_NODES * 4, stream);

  int dev = 0;
  hipGetDevice(&dev);
  int ncu = 0;
  if (hipDeviceGetAttribute(&ncu, hipDeviceAttributeMultiprocessorCount, dev) !=
          hipSuccess ||
      ncu < 8 || ncu > 2048)
    ncu = 256;

  mega_kernel<<<ncu, NTHR, 0, stream>>>(
      x, src, dst, batch, W1, b1, W2, b2, P1, pb1, P2, pb2, bar, cnt, ptr,
      cursor, esrc, bsum, boff, xb, xa, h1, ha, h2, Wt1, Wt2, hg, t1, z, ncu);
}

// Round 7
// 277.381 us; speedup vs baseline: 2.2592x; 2.2592x over previous
//
#include <hip/hip_runtime.h>
#include <hip/hip_bf16.h>

#define N_NODES 50000
#define N_EDGES 800000
#define IN_CH 128
#define HID 256
#define PROJ 128
#define N_GRAPHS 512

typedef short bf16x8 __attribute__((ext_vector_type(8)));
typedef float f32x4 __attribute__((ext_vector_type(4)));

__device__ __forceinline__ float bf2f(unsigned short u) {
  union { unsigned int i; float f; } x;
  x.i = ((unsigned int)u) << 16;
  return x.f;
}
__device__ __forceinline__ unsigned short f2bf(float f) {
  __hip_bfloat16 h = __float2bfloat16(f);  // RNE
  return *reinterpret_cast<unsigned short*>(&h);
}
__device__ __forceinline__ void load_lds16(const void* g, void* l) {
  __builtin_amdgcn_global_load_lds(
      (const __attribute__((address_space(1))) void*)g,
      (__attribute__((address_space(3))) void*)l, 16, 0, 0);
}

// ---------------------------------------------------------------------------
// CSR build
// ---------------------------------------------------------------------------
__global__ __launch_bounds__(256) void count_kernel(const int* __restrict__ dst,
                                                    int* __restrict__ cnt) {
  int e = blockIdx.x * 256 + threadIdx.x;
  if (e < N_EDGES) atomicAdd(&cnt[dst[e]], 1);
}

__global__ __launch_bounds__(256) void scan1_kernel(const int* __restrict__ cnt,
                                                    int* __restrict__ ptr,
                                                    int* __restrict__ bsum) {
  __shared__ int lds[256];
  const int tid = threadIdx.x;
  const int i = blockIdx.x * 256 + tid;
  int v = (i < N_NODES) ? cnt[i] : 0;
  lds[tid] = v;
  __syncthreads();
  for (int off = 1; off < 256; off <<= 1) {
    int t = (tid >= off) ? lds[tid - off] : 0;
    __syncthreads();
    lds[tid] += t;
    __syncthreads();
  }
  if (i < N_NODES) ptr[i] = lds[tid] - v;  // exclusive within block
  if (tid == 255) bsum[blockIdx.x] = lds[255];
}

__global__ __launch_bounds__(256) void scan2_kernel(const int* __restrict__ bsum,
                                                    int* __restrict__ boff,
                                                    int* __restrict__ ptr,
                                                    int nb) {
  __shared__ int lds[256];
  const int tid = threadIdx.x;
  int v = (tid < nb) ? bsum[tid] : 0;
  lds[tid] = v;
  __syncthreads();
  for (int off = 1; off < 256; off <<= 1) {
    int t = (tid >= off) ? lds[tid - off] : 0;
    __syncthreads();
    lds[tid] += t;
    __syncthreads();
  }
  if (tid < nb) boff[tid] = lds[tid] - v;
  if (tid == 255) ptr[N_NODES] = lds[255];
}

// adds block offsets AND writes the fill cursor
__global__ __launch_bounds__(256) void scan3_kernel(int* __restrict__ ptr,
                                                    const int* __restrict__ boff,
                                                    int* __restrict__ cursor) {
  int i = blockIdx.x * 256 + threadIdx.x;
  if (i < N_NODES) {
    int v = ptr[i] + boff[blockIdx.x];
    ptr[i] = v;
    cursor[i] = v;
  }
}

__global__ __launch_bounds__(256) void fill_kernel(const int* __restrict__ src,
                                                   const int* __restrict__ dst,
                                                   int* __restrict__ cursor,
                                                   int* __restrict__ esrc) {
  int e = blockIdx.x * 256 + threadIdx.x;
  if (e < N_EDGES) {
    int pos = atomicAdd(&cursor[dst[e]], 1);
    esrc[pos] = src[e];
  }
}

// ---------------------------------------------------------------------------
// Prep: x f32 -> bf16, W1/W2 [K][256] f32 -> transposed bf16 [256][K]
// ---------------------------------------------------------------------------
#define PREP_T1 (N_NODES * IN_CH / 4)
#define PREP_T2 (IN_CH * HID)
#define PREP_T3 (HID * HID)
__global__ __launch_bounds__(256) void prep_kernel(
    const float* __restrict__ x, const float* __restrict__ W1,
    const float* __restrict__ W2, unsigned short* __restrict__ xb,
    unsigned short* __restrict__ Wt1, unsigned short* __restrict__ Wt2) {
  int i = blockIdx.x * 256 + threadIdx.x;
  if (i < PREP_T1) {
    float4 v = reinterpret_cast<const float4*>(x)[i];
    ushort4 o = {f2bf(v.x), f2bf(v.y), f2bf(v.z), f2bf(v.w)};
    reinterpret_cast<ushort4*>(xb)[i] = o;
  } else if (i < PREP_T1 + PREP_T2) {
    int idx = i - PREP_T1;
    int k = idx / HID, n = idx % HID;
    Wt1[(size_t)n * IN_CH + k] = f2bf(W1[idx]);
  } else if (i < PREP_T1 + PREP_T2 + PREP_T3) {
    int idx = i - PREP_T1 - PREP_T2;
    int k = idx / HID, n = idx % HID;
    Wt2[(size_t)n * HID + k] = f2bf(W2[idx]);
  }
}

// ---------------------------------------------------------------------------
// Paired-node pull gather with fused self-term.
// One wave = 2 adjacent nodes; interleaved 4+4 unrolled edge loops keep
// 8 independent row-loads in flight (attacks the latency bound).
// ---------------------------------------------------------------------------
template <int C>
__global__ __launch_bounds__(256) void gather_kernel(
    const unsigned short* __restrict__ feat, const int* __restrict__ ptr,
    const int* __restrict__ esrc, unsigned short* __restrict__ out) {
  const int lane = threadIdx.x & 63;
  const int wid = blockIdx.x * 4 + (threadIdx.x >> 6);
  const int n0 = wid * 2;
  if (n0 >= N_NODES) return;
  const int n1 = n0 + 1;  // N_NODES is even
  int e0 = __builtin_amdgcn_readfirstlane(ptr[n0]);
  const int end0 = __builtin_amdgcn_readfirstlane(ptr[n0 + 1]);
  int e1 = __builtin_amdgcn_readfirstlane(ptr[n1]);
  const int end1 = __builtin_amdgcn_readfirstlane(ptr[n1 + 1]);

  if constexpr (C == 256) {
    const ushort4* u4 = reinterpret_cast<const ushort4*>(feat);
    auto add = [&](ushort4 v, float* A) {
      A[0] += bf2f(v.x); A[1] += bf2f(v.y); A[2] += bf2f(v.z); A[3] += bf2f(v.w);
    };
    float A[4], B[4];
    {
      ushort4 s0 = u4[(size_t)n0 * 64 + lane];
      ushort4 s1 = u4[(size_t)n1 * 64 + lane];
      A[0] = bf2f(s0.x); A[1] = bf2f(s0.y); A[2] = bf2f(s0.z); A[3] = bf2f(s0.w);
      B[0] = bf2f(s1.x); B[1] = bf2f(s1.y); B[2] = bf2f(s1.z); B[3] = bf2f(s1.w);
    }
    while (e0 + 4 <= end0 && e1 + 4 <= end1) {
      int p0 = esrc[e0], p1 = esrc[e0 + 1], p2 = esrc[e0 + 2], p3 = esrc[e0 + 3];
      int q0 = esrc[e1], q1 = esrc[e1 + 1], q2 = esrc[e1 + 2], q3 = esrc[e1 + 3];
      ushort4 va = u4[(size_t)p0 * 64 + lane], vb = u4[(size_t)p1 * 64 + lane];
      ushort4 vc = u4[(size_t)p2 * 64 + lane], vd = u4[(size_t)p3 * 64 + lane];
      ushort4 wa = u4[(size_t)q0 * 64 + lane], wb = u4[(size_t)q1 * 64 + lane];
      ushort4 wc = u4[(size_t)q2 * 64 + lane], wd = u4[(size_t)q3 * 64 + lane];
      add(va, A); add(vb, A); add(vc, A); add(vd, A);
      add(wa, B); add(wb, B); add(wc, B); add(wd, B);
      e0 += 4; e1 += 4;
    }
    for (; e0 + 4 <= end0; e0 += 4) {
      int p0 = esrc[e0], p1 = esrc[e0 + 1], p2 = esrc[e0 + 2], p3 = esrc[e0 + 3];
      ushort4 va = u4[(size_t)p0 * 64 + lane], vb = u4[(size_t)p1 * 64 + lane];
      ushort4 vc = u4[(size_t)p2 * 64 + lane], vd = u4[(size_t)p3 * 64 + lane];
      add(va, A); add(vb, A); add(vc, A); add(vd, A);
    }
    for (; e0 < end0; ++e0) add(u4[(size_t)esrc[e0] * 64 + lane], A);
    for (; e1 + 4 <= end1; e1 += 4) {
      int q0 = esrc[e1], q1 = esrc[e1 + 1], q2 = esrc[e1 + 2], q3 = esrc[e1 + 3];
      ushort4 wa = u4[(size_t)q0 * 64 + lane], wb = u4[(size_t)q1 * 64 + lane];
      ushort4 wc = u4[(size_t)q2 * 64 + lane], wd = u4[(size_t)q3 * 64 + lane];
      add(wa, B); add(wb, B); add(wc, B); add(wd, B);
    }
    for (; e1 < end1; ++e1) add(u4[(size_t)esrc[e1] * 64 + lane], B);
    ushort4 o0 = {f2bf(A[0]), f2bf(A[1]), f2bf(A[2]), f2bf(A[3])};
    ushort4 o1 = {f2bf(B[0]), f2bf(B[1]), f2bf(B[2]), f2bf(B[3])};
    reinterpret_cast<ushort4*>(out)[(size_t)n0 * 64 + lane] = o0;
    reinterpret_cast<ushort4*>(out)[(size_t)n1 * 64 + lane] = o1;
  } else {
    const ushort2* u2 = reinterpret_cast<const ushort2*>(feat);
    auto add = [&](ushort2 v, float* A) {
      A[0] += bf2f(v.x); A[1] += bf2f(v.y);
    };
    float A[2], B[2];
    {
      ushort2 s0 = u2[(size_t)n0 * 64 + lane];
      ushort2 s1 = u2[(size_t)n1 * 64 + lane];
      A[0] = bf2f(s0.x); A[1] = bf2f(s0.y);
      B[0] = bf2f(s1.x); B[1] = bf2f(s1.y);
    }
    while (e0 + 4 <= end0 && e1 + 4 <= end1) {
      int p0 = esrc[e0], p1 = esrc[e0 + 1], p2 = esrc[e0 + 2], p3 = esrc[e0 + 3];
      int q0 = esrc[e1], q1 = esrc[e1 + 1], q2 = esrc[e1 + 2], q3 = esrc[e1 + 3];
      ushort2 va = u2[(size_t)p0 * 64 + lane], vb = u2[(size_t)p1 * 64 + lane];
      ushort2 vc = u2[(size_t)p2 * 64 + lane], vd = u2[(size_t)p3 * 64 + lane];
      ushort2 wa = u2[(size_t)q0 * 64 + lane], wb = u2[(size_t)q1 * 64 + lane];
      ushort2 wc = u2[(size_t)q2 * 64 + lane], wd = u2[(size_t)q3 * 64 + lane];
      add(va, A); add(vb, A); add(vc, A); add(vd, A);
      add(wa, B); add(wb, B); add(wc, B); add(wd, B);
      e0 += 4; e1 += 4;
    }
    for (; e0 + 4 <= end0; e0 += 4) {
      int p0 = esrc[e0], p1 = esrc[e0 + 1], p2 = esrc[e0 + 2], p3 = esrc[e0 + 3];
      ushort2 va = u2[(size_t)p0 * 64 + lane], vb = u2[(size_t)p1 * 64 + lane];
      ushort2 vc = u2[(size_t)p2 * 64 + lane], vd = u2[(size_t)p3 * 64 + lane];
      add(va, A); add(vb, A); add(vc, A); add(vd, A);
    }
    for (; e0 < end0; ++e0) add(u2[(size_t)esrc[e0] * 64 + lane], A);
    for (; e1 + 4 <= end1; e1 += 4) {
      int q0 = esrc[e1], q1 = esrc[e1 + 1], q2 = esrc[e1 + 2], q3 = esrc[e1 + 3];
      ushort2 wa = u2[(size_t)q0 * 64 + lane], wb = u2[(size_t)q1 * 64 + lane];
      ushort2 wc = u2[(size_t)q2 * 64 + lane], wd = u2[(size_t)q3 * 64 + lane];
      add(wa, B); add(wb, B); add(wc, B); add(wd, B);
    }
    for (; e1 < end1; ++e1) add(u2[(size_t)esrc[e1] * 64 + lane], B);
    ushort2 o0 = {f2bf(A[0]), f2bf(A[1])};
    ushort2 o1 = {f2bf(B[0]), f2bf(B[1])};
    reinterpret_cast<ushort2*>(out)[(size_t)n0 * 64 + lane] = o0;
    reinterpret_cast<ushort2*>(out)[(size_t)n1 * 64 + lane] = o1;
  }
}

// ---------------------------------------------------------------------------
// MFMA GEMM: C[M][256] = relu(A[M][K] @ W + bias). 128x128 tile, 4 waves
// (2x2), BK=32 double-buffered (32 KB LDS -> 4 blocks/CU, all 782 tiles
// co-resident). XOR chunk swizzle via pre-swizzled global source; rows have
// 4 chunks of 16B, swizzle pos = chunk ^ (row&3).
// ---------------------------------------------------------------------------
template <int K, bool RELU>
__global__ __launch_bounds__(256) void mfma_gemm_kernel(
    const unsigned short* __restrict__ A, const unsigned short* __restrict__ Bt,
    const float* __restrict__ bias, unsigned short* __restrict__ C, int M) {
  constexpr int BK = 32, NT = K / BK;
  __shared__ char lds[2 * 2 * 128 * BK * 2];  // 32 KB: 2buf x (A 8K + B 8K)
  const int tid = threadIdx.x;
  const int l = tid & 63;
  const int w = tid >> 6;  // 0..3
  const int wr = w >> 1, wc = w & 1;
  const int row0 = blockIdx.x * 128;
  const int col0 = blockIdx.y * 128;

  const int srow = l >> 2;                 // row within 16-row group
  const int scol = (l & 3) ^ (srow & 3);   // pre-swizzled source chunk

  f32x4 acc[4][4] = {};

  auto stage = [&](int buf, int t) {
    char* baseA = lds + buf * 16384;
    char* baseB = baseA + 8192;
#pragma unroll
    for (int i = 0; i < 2; ++i) {
      const int j = w * 2 + i;          // 16-row group 0..7
      const int rgrp = j * 16 + srow;   // tile row 0..127
      int ra = row0 + rgrp;
      if (ra > M - 1) ra = M - 1;
      load_lds16(A + (size_t)ra * K + t * BK + scol * 8, baseA + j * 1024);
      const int cb = col0 + rgrp;       // N=256 exact
      load_lds16(Bt + (size_t)cb * K + t * BK + scol * 8, baseB + j * 1024);
    }
  };

  auto compute = [&](int buf) {
    char* baseA = lds + buf * 16384;
    char* baseB = baseA + 8192;
    const int kc = l >> 4;  // chunk 0..3
    bf16x8 a[4], b[4];
#pragma unroll
    for (int m = 0; m < 4; ++m) {
      int row = wr * 64 + m * 16 + (l & 15);
      a[m] = *reinterpret_cast<const bf16x8*>(
          baseA + row * 64 + (kc ^ (row & 3)) * 16);
    }
#pragma unroll
    for (int n = 0; n < 4; ++n) {
      int col = wc * 64 + n * 16 + (l & 15);
      b[n] = *reinterpret_cast<const bf16x8*>(
          baseB + col * 64 + (kc ^ (col & 3)) * 16);
    }
#pragma unroll
    for (int m = 0; m < 4; ++m)
#pragma unroll
      for (int n = 0; n < 4; ++n)
        acc[m][n] = __builtin_amdgcn_mfma_f32_16x16x32_bf16(a[m], b[n],
                                                            acc[m][n], 0, 0, 0);
  };

  stage(0, 0);
  __syncthreads();
#pragma unroll
  for (int t = 0; t < NT; ++t) {
    const int cur = t & 1;
    if (t + 1 < NT) stage(cur ^ 1, t + 1);
    compute(cur);
    __syncthreads();
  }

  // epilogue: C/D layout col=lane&15, row=(lane>>4)*4+j
#pragma unroll
  for (int n = 0; n < 4; ++n) {
    int gc = col0 + wc * 64 + n * 16 + (l & 15);
    float bv = bias[gc];
#pragma unroll
    for (int m = 0; m < 4; ++m) {
      int rbase = row0 + wr * 64 + m * 16 + (l >> 4) * 4;
#pragma unroll
      for (int j = 0; j < 4; ++j) {
        int r = rbase + j;
        if (r < M) {
          float v = acc[m][n][j] + bv;
          if (RELU) v = fmaxf(v, 0.f);
          C[(size_t)r * 256 + gc] = f2bf(v);
        }
      }
    }
  }
}

// ---------------------------------------------------------------------------
// Mean-pool per graph (batch sorted). h bf16 -> hg f32. 8x unrolled.
// ---------------------------------------------------------------------------
__global__ __launch_bounds__(HID) void pool_kernel(
    const unsigned short* __restrict__ h, const int* __restrict__ batch,
    float* __restrict__ hgraph) {
  const int g = blockIdx.x;
  const int c = threadIdx.x;
  auto lower_bound = [&](int key) {
    int lo = 0, hi = N_NODES;
    while (lo < hi) {
      int mid = (lo + hi) >> 1;
      if (batch[mid] < key) lo = mid + 1; else hi = mid;
    }
    return lo;
  };
  const int s = lower_bound(g);
  const int e = lower_bound(g + 1);
  float a0 = 0.f, a1 = 0.f, a2 = 0.f, a3 = 0.f;
  float a4 = 0.f, a5 = 0.f, a6 = 0.f, a7 = 0.f;
  int n = s;
  for (; n + 8 <= e; n += 8) {
    a0 += bf2f(h[(size_t)(n + 0) * HID + c]);
    a1 += bf2f(h[(size_t)(n + 1) * HID + c]);
    a2 += bf2f(h[(size_t)(n + 2) * HID + c]);
    a3 += bf2f(h[(size_t)(n + 3) * HID + c]);
    a4 += bf2f(h[(size_t)(n + 4) * HID + c]);
    a5 += bf2f(h[(size_t)(n + 5) * HID + c]);
    a6 += bf2f(h[(size_t)(n + 6) * HID + c]);
    a7 += bf2f(h[(size_t)(n + 7) * HID + c]);
  }
  for (; n < e; ++n) a0 += bf2f(h[(size_t)n * HID + c]);
  float acc = ((a0 + a1) + (a2 + a3)) + ((a4 + a5) + (a6 + a7));
  float cnt = fmaxf((float)(e - s), 1.0f);
  hgraph[g * HID + c] = acc / cnt;
}

// ---------------------------------------------------------------------------
// Fused projection head: z = relu(hg @ P1 + pb1) @ P2 + pb2.
// One block = 8 graphs; t1 kept in LDS (no global round-trip).
// ---------------------------------------------------------------------------
__global__ __launch_bounds__(256) void head_kernel(
    const float* __restrict__ hg, const float* __restrict__ P1,
    const float* __restrict__ pb1, const float* __restrict__ P2,
    const float* __restrict__ pb2, float* __restrict__ z) {
  __shared__ float hs[8][256];
  __shared__ float ts[8][256];
  const int tid = threadIdx.x;
  const int g0 = blockIdx.x * 8;
  for (int i = tid; i < 8 * 256; i += 256)
    hs[i >> 8][i & 255] = hg[(size_t)g0 * 256 + i];
  __syncthreads();
  {
    float acc[8];
    float bv = pb1[tid];
#pragma unroll
    for (int r = 0; r < 8; ++r) acc[r] = bv;
    for (int k = 0; k < 256; ++k) {
      float wv = P1[k * 256 + tid];
#pragma unroll
      for (int r = 0; r < 8; ++r) acc[r] = fmaf(hs[r][k], wv, acc[r]);
    }
#pragma unroll
    for (int r = 0; r < 8; ++r) ts[r][tid] = fmaxf(acc[r], 0.f);
  }
  __syncthreads();
  {
    const int c = tid & 127;
    const int r0 = (tid >> 7) * 4;
    float acc[4];
    float bv = pb2[c];
#pragma unroll
    for (int r = 0; r < 4; ++r) acc[r] = bv;
    for (int k = 0; k < 256; ++k) {
      float wv = P2[k * 128 + c];
#pragma unroll
      for (int r = 0; r < 4; ++r) acc[r] = fmaf(ts[r0 + r][k], wv, acc[r]);
    }
#pragma unroll
    for (int r = 0; r < 4; ++r) z[(size_t)(g0 + r0 + r) * 128 + c] = acc[r];
  }
}

// ---------------------------------------------------------------------------
extern "C" void kernel_launch(void* const* d_in, const int* in_sizes, int n_in,
                              void* d_out, int out_size, void* d_ws,
                              size_t ws_size, hipStream_t stream) {
  const float* x = (const float*)d_in[0];
  const int* edge = (const int*)d_in[1];
  const int* batch = (const int*)d_in[2];
  const float* W1 = (const float*)d_in[3];
  const float* b1 = (const float*)d_in[4];
  const float* W2 = (const float*)d_in[5];
  const float* b2 = (const float*)d_in[6];
  const float* P1 = (const float*)d_in[7];
  const float* pb1 = (const float*)d_in[8];
  const float* P2 = (const float*)d_in[9];
  const float* pb2 = (const float*)d_in[10];
  const int* src = edge;
  const int* dst = edge + N_EDGES;

  char* ws = (char*)d_ws;
  size_t off = 0;
  auto alloc = [&](size_t bytes) {
    void* p = ws + off;
    off += (bytes + 255) & ~(size_t)255;
    return p;
  };
  unsigned short* xb  = (unsigned short*)alloc((size_t)N_NODES * IN_CH * 2);
  unsigned short* xa  = (unsigned short*)alloc((size_t)N_NODES * IN_CH * 2);
  unsigned short* h1  = (unsigned short*)alloc((size_t)N_NODES * HID * 2);
  unsigned short* ha  = (unsigned short*)alloc((size_t)N_NODES * HID * 2);
  unsigned short* h2  = (unsigned short*)alloc((size_t)N_NODES * HID * 2);
  unsigned short* Wt1 = (unsigned short*)alloc((size_t)HID * IN_CH * 2);
  unsigned short* Wt2 = (unsigned short*)alloc((size_t)HID * HID * 2);
  float* hg = (float*)alloc((size_t)N_GRAPHS * HID * 4);
  int* ptr = (int*)alloc((size_t)(N_NODES + 1) * 4);
  int* cursor = (int*)alloc((size_t)N_NODES * 4);  // count buf, then cursors
  int* esrc = (int*)alloc((size_t)N_EDGES * 4);
  int* bsum = (int*)alloc(256 * 4);
  int* boff = (int*)alloc(256 * 4);
  float* z = (float*)d_out;

  const int EB = (N_EDGES + 255) / 256;
  const int NB = (N_NODES + 255) / 256;  // 196

  // --- CSR build (dst-indexed) ---
  hipMemsetAsync(cursor, 0, (size_t)N_NODES * 4, stream);
  count_kernel<<<EB, 256, 0, stream>>>(dst, cursor);
  scan1_kernel<<<NB, 256, 0, stream>>>(cursor, ptr, bsum);
  scan2_kernel<<<1, 256, 0, stream>>>(bsum, boff, ptr, NB);
  scan3_kernel<<<NB, 256, 0, stream>>>(ptr, boff, cursor);
  fill_kernel<<<EB, 256, 0, stream>>>(src, dst, cursor, esrc);

  // --- prep (x->bf16, W1/W2 -> transposed bf16) ---
  prep_kernel<<<(PREP_T1 + PREP_T2 + PREP_T3 + 255) / 256, 256, 0, stream>>>(
      x, W1, W2, xb, Wt1, Wt2);

  // --- Layer 1 ---
  gather_kernel<IN_CH>
      <<<(N_NODES / 2 + 3) / 4, 256, 0, stream>>>(xb, ptr, esrc, xa);
  {
    dim3 grid((N_NODES + 127) / 128, 2);
    mfma_gemm_kernel<IN_CH, true><<<grid, 256, 0, stream>>>(xa, Wt1, b1, h1,
                                                            N_NODES);
  }

  // --- Layer 2 ---
  gather_kernel<HID>
      <<<(N_NODES / 2 + 3) / 4, 256, 0, stream>>>(h1, ptr, esrc, ha);
  {
    dim3 grid((N_NODES + 127) / 128, 2);
    mfma_gemm_kernel<HID, true><<<grid, 256, 0, stream>>>(ha, Wt2, b2, h2,
                                                          N_NODES);
  }

  // --- Mean pool ---
  pool_kernel<<<N_GRAPHS, HID, 0, stream>>>(h2, batch, hg);

  // --- Fused projection head ---
  head_kernel<<<N_GRAPHS / 8, 256, 0, stream>>>(hg, P1, pb1, P2, pb2, z);
}